// Round 1
// baseline (123.546 us; speedup 1.0000x reference)
//
#include <hip/hip_runtime.h>
#include <hip/hip_bf16.h>

// bs=2, seq=2048, d_model=512, heads=8, d_k=64, WINDOW=2
#define SEQ 2048
#define DM  512
#define BS  2
#define NH  8
#define DK  64
#define MROWS (BS * SEQ)   // 4096
#define GK 64              // GEMM K-tile (two 16x16x32 MFMA k-steps per barrier pair)

typedef __attribute__((ext_vector_type(8))) short bf16x8;
typedef __attribute__((ext_vector_type(4))) float f32x4;

__device__ __forceinline__ unsigned short f2bf(float f) {
    unsigned int u = __float_as_uint(f);
    u += 0x7fff + ((u >> 16) & 1);
    return (unsigned short)(u >> 16);
}
__device__ __forceinline__ float bf2f(unsigned short b) {
    return __uint_as_float((unsigned int)b << 16);
}

// async global->LDS, 16B per lane. LDS dest must be wave-uniform base + lane*16.
#define GLDS16(g, l) __builtin_amdgcn_global_load_lds( \
    (const __attribute__((address_space(1))) void*)(g), \
    (__attribute__((address_space(3))) void*)(unsigned int)(unsigned long long)(l), 16, 0, 0)

// ---------------- prep (small): transpose+cvt weights; init vsum = SEQ*bv ----------------
__global__ __launch_bounds__(256) void prep_w(const float* __restrict__ Wq, const float* __restrict__ Wk,
                                              const float* __restrict__ Wv, const float* __restrict__ Wo,
                                              const float* __restrict__ bv_,
                                              unsigned short* __restrict__ WqT, unsigned short* __restrict__ WkT,
                                              unsigned short* __restrict__ WvT, unsigned short* __restrict__ WoT,
                                              float* __restrict__ vsum)
{
    __shared__ float tile[32][33];
    const int bid = blockIdx.x;            // 0..1023
    if (bid == 0) {
        #pragma unroll
        for (int t = 0; t < 4; ++t) {
            const int idx = threadIdx.x * 4 + t;           // 0..1023
            vsum[idx] = (float)SEQ * bv_[idx & (DM - 1)];
        }
    }
    const int z = bid >> 8;
    const int tl = bid & 255;
    const float* W = (z == 0) ? Wq : (z == 1) ? Wk : (z == 2) ? Wv : Wo;
    unsigned short* T = (z == 0) ? WqT : (z == 1) ? WkT : (z == 2) ? WvT : WoT;
    const int n0 = (tl & 15) * 32, k0 = (tl >> 4) * 32;
    const int tx = threadIdx.x & 31;
    const int ty = threadIdx.x >> 5;
    #pragma unroll
    for (int r = 0; r < 32; r += 8)
        tile[ty + r][tx] = W[(size_t)(k0 + ty + r) * DM + n0 + tx];
    __syncthreads();
    #pragma unroll
    for (int r = 0; r < 32; r += 8)
        T[(size_t)(n0 + ty + r) * DM + k0 + tx] = f2bf(tile[tx][ty + r]);
}

// ---------------- QKV projection GEMM with fused f32->bf16 A-staging ----------------
// C(bf16, 4096x512) = cvt_bf16(A f32) @ BT(bf16)^T + bias.  Tile 64x128, GK=64.
// 1D grid 768, XCD-swizzled: all 4 n-blocks of one (z,m) strip share blockIdx%8
// (same XCD) so the 128KB f32 A-strip is L2-resident after the first reader.
// A staged via registers (load f32 -> RNE cvt -> ds_write); B via global_load_lds.
// z==2 (V) also accumulates raw per-column sums into vsum (bias pre-folded).
__global__ __launch_bounds__(256) void gemm_qkv_cvt(const float* __restrict__ q,
                                                    const float* __restrict__ k,
                                                    const float* __restrict__ v,
                                                    const unsigned short* __restrict__ WqT,
                                                    const unsigned short* __restrict__ WkT,
                                                    const unsigned short* __restrict__ WvT,
                                                    const float* __restrict__ bq, const float* __restrict__ bk,
                                                    const float* __restrict__ bvp,
                                                    unsigned short* __restrict__ Qb, unsigned short* __restrict__ Kb,
                                                    unsigned short* __restrict__ Vb, float* __restrict__ vsum)
{
    // A region: [kk][row64][32] = 4096 shorts (8 KB); B region at 4096: [kk][row128][32] (16 KB)
    __shared__ unsigned short S[12288];

    // XCD swizzle decode: g = xcd + 8*n + 32*t; strip = t*8+xcd; z = strip/64, m = strip%64
    const int g = blockIdx.x;                 // 0..767
    const int xcd   = g & 7;
    const int n_idx = (g >> 3) & 3;
    const int t     = g >> 5;                 // 0..23
    const int strip = t * 8 + xcd;            // 0..191
    const int z     = strip >> 6;             // 0..2
    const int m0    = (strip & 63) * 64;
    const int n0    = n_idx * 128;

    const float* Af; const unsigned short* BT; const float* bias; unsigned short* C; float* vs;
    if (z == 0)      { Af = q; BT = WqT; bias = bq; C = Qb; vs = nullptr; }
    else if (z == 1) { Af = k; BT = WkT; bias = bk; C = Kb; vs = nullptr; }
    else             { Af = v; BT = WvT; bias = bvp; C = Vb; vs = vsum; }

    const int tid  = threadIdx.x;
    const int lane = tid & 63;
    const int wave = tid >> 6;
    const int wm = (wave & 1) * 32;       // wave tile 32x64
    const int wn = (wave >> 1) * 64;
    const int l15 = lane & 15;
    const int q8  = (lane >> 4) * 8;

    f32x4 acc[2][4];
    #pragma unroll
    for (int i = 0; i < 2; ++i)
        #pragma unroll
        for (int j = 0; j < 4; ++j)
            acc[i][j] = (f32x4){0.f, 0.f, 0.f, 0.f};

    // A-staging mapping: pass p in [0,4): row = p*16 + (tid>>4), cols (tid&15)*4 .. +3
    const int arow = tid >> 4;             // 0..15
    const int akl  = (tid & 15) * 4;       // 0..60
    const int awoff = ((akl >> 5) * 2048) + (akl & 31);   // + row*32 (shorts); kk stride 2048

    // B chunks: 1024 x 16B per K-tile, 4 per thread.  LDS B region [kk][n][32].
    const unsigned short* gb[4];
    unsigned short* lb[4];
    #pragma unroll
    for (int it = 0; it < 4; ++it) {
        const int c = tid + it * 256;
        const int n  = (c >> 2) & 127;
        const int kk = c >> 9;
        gb[it] = BT + (size_t)(n0 + n) * DM + kk * 32 + (c & 3) * 8;
        lb[it] = &S[4096 + c * 8];
    }

    for (int k0 = 0; k0 < DM; k0 += GK) {
        #pragma unroll
        for (int it = 0; it < 4; ++it)
            GLDS16(gb[it] + k0, lb[it]);

        float4 av[4];
        #pragma unroll
        for (int p = 0; p < 4; ++p)
            av[p] = *(const float4*)(Af + (size_t)(m0 + p * 16 + arow) * DM + k0 + akl);
        #pragma unroll
        for (int p = 0; p < 4; ++p) {
            ushort4 o;
            o.x = f2bf(av[p].x); o.y = f2bf(av[p].y); o.z = f2bf(av[p].z); o.w = f2bf(av[p].w);
            *(ushort4*)&S[awoff + (p * 16 + arow) * 32] = o;
        }
        __syncthreads();

        #pragma unroll
        for (int kk = 0; kk < 2; ++kk) {
            bf16x8 af[2], bfr[4];
            #pragma unroll
            for (int i = 0; i < 2; ++i)
                af[i] = *(const bf16x8*)&S[kk * 2048 + (wm + i * 16 + l15) * 32 + q8];
            #pragma unroll
            for (int j = 0; j < 4; ++j)
                bfr[j] = *(const bf16x8*)&S[4096 + kk * 4096 + (wn + j * 16 + l15) * 32 + q8];
            #pragma unroll
            for (int i = 0; i < 2; ++i)
                #pragma unroll
                for (int j = 0; j < 4; ++j)
                    acc[i][j] = __builtin_amdgcn_mfma_f32_16x16x32_bf16(af[i], bfr[j], acc[i][j], 0, 0, 0);
        }
        __syncthreads();
    }

    // epilogue: C/D layout col=lane&15, row=(lane>>4)*4+reg; bf16 store
    #pragma unroll
    for (int j = 0; j < 4; ++j) {
        const int col = n0 + wn + j * 16 + l15;
        const float bv = bias[col];
        #pragma unroll
        for (int i = 0; i < 2; ++i) {
            const int rbase = m0 + wm + i * 16 + (lane >> 4) * 4;
            #pragma unroll
            for (int r = 0; r < 4; ++r)
                C[(size_t)(rbase + r) * DM + col] = f2bf(acc[i][j][r] + bv);
        }
    }

    if (vs) {
        const int b = m0 >> 11;   // 64-row tiles never straddle the batch boundary
        #pragma unroll
        for (int j = 0; j < 4; ++j) {
            float part = 0.f;
            #pragma unroll
            for (int i = 0; i < 2; ++i)
                #pragma unroll
                for (int r = 0; r < 4; ++r)
                    part += acc[i][j][r];
            part += __shfl_xor(part, 16, 64);
            part += __shfl_xor(part, 32, 64);
            if ((lane >> 4) == 0)
                atomicAdd(&vs[b * DM + n0 + wn + j * 16 + l15], part);
        }
    }
}

// ---------------- fused MFMA band attention + output projection ----------------
// Grid 256 = one block per (b, 16-row q-tile); 512 threads = 8 waves.
// Phase 1: wave h runs band attention for head h, writes its 16x64 bf16 concat
//          slice into LDS Wc[16][520] (row pad 8 shorts -> +4 bank shift/row ->
//          phase-2 ds_read_b128 A-frags hit 8 distinct 4-bank groups, conflict-free).
// Phase 2: wave w computes output n-slice [w*64, w*64+64): A-frags from Wc,
//          B-frags (WoT rows, k-contiguous) straight from global (0.5MB, L2-resident).
//          ks=0 B-frags prefetched before phase 1 to hide L2 latency.
// Eliminates: concat HBM roundtrip (8MB), one kernel launch + drain bubble,
// gemm_out's 16 barriers and LDS staging.
__global__ __launch_bounds__(512) void attn_out(const unsigned short* __restrict__ Qb,
                                                const unsigned short* __restrict__ Kb,
                                                const unsigned short* __restrict__ Vb,
                                                const float* __restrict__ vsum,
                                                const unsigned short* __restrict__ WoT,
                                                const float* __restrict__ bo,
                                                float* __restrict__ out)
{
    __shared__ unsigned short Wc[16][520];     // concat tile, padded (1040 B rows)
    __shared__ unsigned short Wl[NH][16 * 32]; // per-wave band-weight scratch

    const int tid  = threadIdx.x;
    const int lane = tid & 63;
    const int h    = tid >> 6;                 // wave index == head (phase 1) == n-slice (phase 2)
    const int l15  = lane & 15;
    const int quad = lane >> 4;                // 0..3
    const int b  = blockIdx.x >> 7;
    const int q0 = (blockIdx.x & 127) * 16;
    const size_t rowbase = (size_t)b * SEQ;
    const int dbase = h * DK;

    // -------- phase-2 first-K-step B prefetch (independent of attention) --------
    const unsigned short* Bp = WoT + (size_t)(h * 64 + l15) * DM + quad * 8;
    bf16x8 bpre[4];
    #pragma unroll
    for (int j = 0; j < 4; ++j)
        bpre[j] = *(const bf16x8*)(Bp + (size_t)j * 16 * DM);

    // -------- phase 1: band attention for head h --------
    const unsigned short* qrow = Qb + (rowbase + q0 + l15) * DM + dbase + quad * 8;
    const bf16x8 aq0 = *(const bf16x8*)(qrow);
    const bf16x8 aq1 = *(const bf16x8*)(qrow + 32);

    f32x4 sc[2];
    #pragma unroll
    for (int t = 0; t < 2; ++t) {
        int kp = q0 - 4 + t * 16 + l15;
        kp = min(max(kp, 0), SEQ - 1);
        const unsigned short* krow = Kb + (rowbase + kp) * DM + dbase + quad * 8;
        const bf16x8 b0 = *(const bf16x8*)(krow);
        const bf16x8 b1 = *(const bf16x8*)(krow + 32);
        f32x4 z = (f32x4){0.f, 0.f, 0.f, 0.f};
        z = __builtin_amdgcn_mfma_f32_16x16x32_bf16(aq0, b0, z, 0, 0, 0);
        sc[t] = __builtin_amdgcn_mfma_f32_16x16x32_bf16(aq1, b1, z, 0, 0, 0);
    }

    float dsum[4] = {0.f, 0.f, 0.f, 0.f};
    #pragma unroll
    for (int t = 0; t < 2; ++t) {
        const int kpos = q0 - 4 + t * 16 + l15;   // unclamped
        #pragma unroll
        for (int r = 0; r < 4; ++r) {
            const int qq = q0 + quad * 4 + r;
            const int mn = min(qq, kpos), mx = qq + kpos - mn;
            const float cnt = (float)(min(mn + 2, SEQ - 1) - max(mx - 2, 0) + 1);
            const float cw = (kpos >= 0 && kpos < SEQ && (mx - mn) <= 4) ? cnt * 0.125f : 0.f;
            const float w = expf(sc[t][r] * cw) - 1.f;   // cw==0 -> exactly 0
            const unsigned short wb = f2bf(w);
            Wl[h][(quad * 4 + r) * 32 + t * 16 + l15] = wb;
            dsum[r] += bf2f(wb);
        }
    }
    #pragma unroll
    for (int off = 1; off <= 8; off <<= 1)
        #pragma unroll
        for (int r = 0; r < 4; ++r)
            dsum[r] += __shfl_xor(dsum[r], off, 64);

    __syncthreads();
    const bf16x8 aw = *(const bf16x8*)&Wl[h][l15 * 32 + quad * 8];

    #pragma unroll
    for (int nt = 0; nt < 4; ++nt) {
        const int d = dbase + nt * 16 + l15;
        bf16x8 bv_;
        #pragma unroll
        for (int j = 0; j < 8; ++j) {
            int kr = q0 - 4 + quad * 8 + j;
            kr = min(max(kr, 0), SEQ - 1);       // pad rows get w=0
            bv_[j] = (short)Vb[(rowbase + kr) * DM + d];
        }
        f32x4 z = (f32x4){0.f, 0.f, 0.f, 0.f};
        const f32x4 o = __builtin_amdgcn_mfma_f32_16x16x32_bf16(aw, bv_, z, 0, 0, 0);
        const float vs = vsum[b * DM + d];
        #pragma unroll
        for (int r = 0; r < 4; ++r) {
            const float den = (float)SEQ + dsum[r];
            Wc[quad * 4 + r][d] = f2bf((vs + o[r]) / den);
        }
    }

    __syncthreads();   // Wc complete

    // -------- phase 2: out[q0..q0+15, n0..n0+63] = Wc @ WoT^T + bo --------
    f32x4 acc[4];
    #pragma unroll
    for (int j = 0; j < 4; ++j)
        acc[j] = (f32x4){0.f, 0.f, 0.f, 0.f};

    #pragma unroll
    for (int ks = 0; ks < 16; ++ks) {
        const bf16x8 af = *(const bf16x8*)&Wc[l15][ks * 32 + quad * 8];
        #pragma unroll
        for (int j = 0; j < 4; ++j) {
            const bf16x8 bw = (ks == 0) ? bpre[j]
                            : *(const bf16x8*)(Bp + (size_t)j * 16 * DM + ks * 32);
            acc[j] = __builtin_amdgcn_mfma_f32_16x16x32_bf16(af, bw, acc[j], 0, 0, 0);
        }
    }

    #pragma unroll
    for (int j = 0; j < 4; ++j) {
        const int col = h * 64 + j * 16 + l15;
        const float bov = bo[col];
        #pragma unroll
        for (int r = 0; r < 4; ++r)
            out[(rowbase + q0 + quad * 4 + r) * DM + col] = acc[j][r] + bov;
    }
}

extern "C" void kernel_launch(void* const* d_in, const int* in_sizes, int n_in,
                              void* d_out, int out_size, void* d_ws, size_t ws_size,
                              hipStream_t stream) {
    const float* q  = (const float*)d_in[0];
    const float* k  = (const float*)d_in[1];
    const float* v  = (const float*)d_in[2];
    const float* Wq = (const float*)d_in[3];
    const float* bq = (const float*)d_in[4];
    const float* Wk = (const float*)d_in[5];
    const float* bk = (const float*)d_in[6];
    const float* Wv = (const float*)d_in[7];
    const float* bv = (const float*)d_in[8];
    const float* Wo = (const float*)d_in[9];
    const float* bo = (const float*)d_in[10];

    const size_t NE = (size_t)MROWS * DM;  // 2,097,152

    float* vsum = (float*)d_ws;                        // 1024 floats
    unsigned short* Qb     = (unsigned short*)(vsum + 1024);
    unsigned short* Kb     = Qb + NE;
    unsigned short* Vb     = Kb + NE;
    unsigned short* WqT    = Vb + NE;
    unsigned short* WkT    = WqT + DM * DM;
    unsigned short* WvT    = WkT + DM * DM;
    unsigned short* WoT    = WvT + DM * DM;

    // 1. weight transpose + vsum init (small)
    prep_w<<<1024, 256, 0, stream>>>(Wq, Wk, Wv, Wo, bv, WqT, WkT, WvT, WoT, vsum);

    // 2. Q/K/V projection GEMMs, fused f32->bf16 A-staging + fused V column-sum
    //    64x128 tiles, 1D grid 768 XCD-swizzled (3/CU balanced, A-strips L2-local)
    gemm_qkv_cvt<<<768, 256, 0, stream>>>(q, k, v, WqT, WkT, WvT,
                                          bq, bk, bv, Qb, Kb, Vb, vsum);

    // 3. fused band attention + output projection (256 blocks x 8 waves, 1/CU)
    attn_out<<<256, 512, 0, stream>>>(Qb, Kb, Vb, vsum, WoT, bo, (float*)d_out);
}